// Round 11
// baseline (356.121 us; speedup 1.0000x reference)
//
#include <hip/hip_runtime.h>
#include <hip/hip_bf16.h>
#include <math.h>

#define BS   8192   // batch*seq tokens
#define SEQQ 2048
#define HID  1024
#define ES   2048   // n_exp * slots
#define FFN  2730
#define FFNP 2752   // FFN padded to multiple of 32
#define NEXP 16
#define SLOT 128

typedef __attribute__((ext_vector_type(4))) float  f32x4;
typedef __attribute__((ext_vector_type(8))) short  short8;
typedef __attribute__((ext_vector_type(4))) short  short4v;

__device__ __forceinline__ short f2bf(float f) {
    union { float f; unsigned u; } v; v.f = f;
    unsigned r = v.u + 0x7fffu + ((v.u >> 16) & 1u);   // RNE
    return (short)(r >> 16);
}

// GEMM LDS swizzle (shorts). Row = 32 shorts, slot' = slot ^ ((row>>1)&3).
// Verified conflict-free rounds 4-10 (SQ_LDS_BANK_CONFLICT == 0).
__device__ __forceinline__ int swz(int row, int kk) {
    return (row << 5) + ((((kk >> 3) ^ (row >> 1)) & 3) << 3) + (kk & 7);
}

#define GLD16(gp, lp)                                                   \
    __builtin_amdgcn_global_load_lds(                                   \
        (__attribute__((address_space(1))) void*)(gp),                  \
        (__attribute__((address_space(3))) void*)(lp), 16, 0, 0)

// Transpose-tile swizzle for 64es x 256tok LDS tiles (see round 7).
__device__ __forceinline__ int tsw(int e) { return ((e >> 3) ^ e) & 7; }

// ---------- fused prep: exp(logits) -> DT [ES][BS] + CB [BS][ES] + sum partials ----------
__global__ __launch_bounds__(256) void exp_stats_kernel(const float* __restrict__ L,
                                                        short* __restrict__ DT,
                                                        short* __restrict__ CB,
                                                        float* __restrict__ rowpart,
                                                        float* __restrict__ colpart)
{
    const int t0 = (blockIdx.x & 31) << 8;       // 256-token tile
    const int et = blockIdx.x >> 5;              // es tile 0..31
    const int e0 = et << 6;                      // 64-es tile
    const int tid = threadIdx.x;
    const int lane = tid & 63;
    const int row = tid >> 3;                    // 0..31
    const int seg = tid & 7;                     // 0..7

    __shared__ short T[64 * 256];
    __shared__ float CP[4][64];

    float colacc[8];
    #pragma unroll
    for (int j = 0; j < 8; ++j) colacc[j] = 0.f;

    #pragma unroll
    for (int p = 0; p < 8; ++p) {
        const int tok = p * 32 + row;
        const float* src = L + (size_t)(t0 + tok) * ES + e0 + seg * 8;
        f32x4 a = *reinterpret_cast<const f32x4*>(src);
        f32x4 b = *reinterpret_cast<const f32x4*>(src + 4);
        float ex[8];
        #pragma unroll
        for (int j = 0; j < 4; ++j) ex[j]     = __expf(a[j]);
        #pragma unroll
        for (int j = 0; j < 4; ++j) ex[4 + j] = __expf(b[j]);
        float rs = 0.f;
        #pragma unroll
        for (int j = 0; j < 8; ++j) {
            const int e = seg * 8 + j;
            T[e * 256 + (tok ^ (((seg ^ j) & 7) << 3))] = f2bf(ex[j]);
            colacc[j] += ex[j];
            rs += ex[j];
        }
        rs += __shfl_xor(rs, 1, 64);
        rs += __shfl_xor(rs, 2, 64);
        rs += __shfl_xor(rs, 4, 64);
        if (seg == 0) rowpart[(size_t)(t0 + tok) * 32 + et] = rs;
    }
    #pragma unroll
    for (int j = 0; j < 8; ++j) {
        colacc[j] += __shfl_xor(colacc[j], 8, 64);
        colacc[j] += __shfl_xor(colacc[j], 16, 64);
        colacc[j] += __shfl_xor(colacc[j], 32, 64);
    }
    if ((lane >> 3) == 0) {
        #pragma unroll
        for (int j = 0; j < 8; ++j) CP[tid >> 6][(lane & 7) * 8 + j] = colacc[j];
    }
    __syncthreads();
    if (tid < 64)
        colpart[(size_t)(t0 >> 8) * ES + e0 + tid] =
            CP[0][tid] + CP[1][tid] + CP[2][tid] + CP[3][tid];
    // DT write-out (tok-contiguous 16B chunks per es row)
    {
        const int e = tid >> 2, ts = tid & 3;
        const int sw = tsw(e) << 3;
        const size_t o = (size_t)(e0 + e) * BS + t0 + ts * 64;
        #pragma unroll
        for (int q = 0; q < 8; ++q) {
            short8 w = *reinterpret_cast<const short8*>(&T[e * 256 + ((ts * 64 + q * 8) ^ sw)]);
            *reinterpret_cast<short8*>(&DT[o + q * 8]) = w;
        }
    }
    // CB write-out (es-contiguous 16B chunks per token)
    {
        #pragma unroll
        for (int p = 0; p < 8; ++p) {
            const int tok = p * 32 + row;
            short8 w;
            #pragma unroll
            for (int j = 0; j < 8; ++j) {
                const int e = seg * 8 + j;
                w[j] = T[e * 256 + (tok ^ (((seg ^ j) & 7) << 3))];
            }
            *reinterpret_cast<short8*>(&CB[(size_t)(t0 + tok) * ES + e0 + seg * 8]) = w;
        }
    }
}

__global__ __launch_bounds__(256) void rrow_kernel(const float* __restrict__ rowpart,
                                                   float* __restrict__ crcp)
{
    const int t = blockIdx.x * 256 + threadIdx.x;
    const float* p = rowpart + (size_t)t * 32;
    float s = 0.f;
    #pragma unroll
    for (int j = 0; j < 8; ++j) {
        f32x4 v = *reinterpret_cast<const f32x4*>(p + 4 * j);
        s += (v[0] + v[1]) + (v[2] + v[3]);
    }
    crcp[t] = 1.f / s;
}

__global__ __launch_bounds__(256) void rcol_kernel(const float* __restrict__ colpart,
                                                   float* __restrict__ drcp)
{
    const int g = blockIdx.x * 256 + threadIdx.x;   // b*2048 + c
    const int b = g >> 11, c = g & 2047;
    float s = 0.f;
    #pragma unroll
    for (int ch = 0; ch < 8; ++ch)
        s += colpart[(size_t)(b * 8 + ch) * ES + c];
    drcp[g] = 1.f / s;
}

// ---------- x fp32 [8192][1024] -> xT bf16 [1024][8192] ----------
__global__ __launch_bounds__(256) void transpose_x(const float* __restrict__ X,
                                                   short* __restrict__ XT)
{
    __shared__ short T[64][72];
    const int tid = threadIdx.x;
    const int k0 = blockIdx.x * 64;
    const int n0 = blockIdx.y * 64;
    {
        const int kk = tid >> 2;
        const int nn = (tid & 3) * 16;
        const float* src = X + (size_t)(k0 + kk) * HID + n0 + nn;
        #pragma unroll
        for (int j = 0; j < 4; ++j) {
            f32x4 v = *reinterpret_cast<const f32x4*>(src + 4 * j);
            short4v s;
            #pragma unroll
            for (int i = 0; i < 4; ++i) s[i] = f2bf(v[i]);
            *reinterpret_cast<short4v*>(&T[kk][nn + 4 * j]) = s;
        }
    }
    __syncthreads();
    {
        const int nn  = tid >> 2;
        const int kk4 = (tid & 3) * 16;
        short8 w0, w1;
        #pragma unroll
        for (int i = 0; i < 8; ++i) w0[i] = T[kk4 + i][nn];
        #pragma unroll
        for (int i = 0; i < 8; ++i) w1[i] = T[kk4 + 8 + i][nn];
        size_t o = (size_t)(n0 + nn) * BS + k0 + kk4;
        *reinterpret_cast<short8*>(&XT[o])     = w0;
        *reinterpret_cast<short8*>(&XT[o + 8]) = w1;
    }
}

// ---------- xt = bf16(sum_z drcp[z>>1][c] * part[z][c][h]) (8 K-splits, 2/batch) ----------
__global__ __launch_bounds__(256) void reduce_xt(const float* __restrict__ P,
                                                 const float* __restrict__ drcp,
                                                 short* __restrict__ xt)
{
    const size_t i = ((size_t)blockIdx.x * 256 + threadIdx.x) * 4;
    const int c = (int)(i >> 10);
    const size_t CH = (size_t)ES * HID;
    f32x4 s[8];
    #pragma unroll
    for (int z = 0; z < 8; ++z)
        s[z] = *reinterpret_cast<const f32x4*>(&P[i + (size_t)z * CH]);
    float r[8];
    #pragma unroll
    for (int z = 0; z < 8; ++z) r[z] = drcp[(z >> 1) * ES + c];
    short4v o;
    #pragma unroll
    for (int j = 0; j < 4; ++j) {
        float v = 0.f;
        #pragma unroll
        for (int z = 0; z < 8; ++z) v += s[z][j] * r[z];
        o[j] = f2bf(v);
    }
    *reinterpret_cast<short4v*>(&xt[i]) = o;
}

// ---------------- bf16 MFMA GEMM body (round-9 schedule) ----------------
// gload_lds A (+B if BT) dbuf, 1 barrier/step; float-B reg-staged depth-1.
// EPI: 0 none, 1 silu, 2 row-scale by aux[m].
// PADW: store n >= Ndim too (acc==0 there since B staged 0).
template<int BM, int BN, int EPI, bool NBND, bool KBND, bool BT, bool CT, bool PADW,
         typename TB, typename TC>
__device__ __forceinline__
void gemm_body(const short* __restrict__ A, const TB* __restrict__ B,
               TC* __restrict__ C, int Ndim, int Kdim,
               int lda, int ldb, int ldc,
               long sA, long sB, long sC, const float* __restrict__ aux)
{
    constexpr int BK = 32;
    A += (size_t)blockIdx.z * sA;
    B += (size_t)blockIdx.z * sB;
    C += (size_t)blockIdx.z * sC;
    const int m0 = blockIdx.x * BM;
    const int n0 = blockIdx.y * BN;
    const int tid  = threadIdx.x;
    const int lane = tid & 63;
    const int wid  = tid >> 6;
    const int wm = wid >> 1, wn = wid & 1;
    constexpr int WMT = BM / 2, WNT = BN / 2, MI = WMT / 16, NI = WNT / 16;
    constexpr int PA = BM / 64;
    constexpr int PB = BN / 64;

    __shared__ __align__(16) short As0[BM * 32], As1[BM * 32];
    __shared__ __align__(16) short Bs0[BN * 32], Bs1[BN * 32];

    f32x4 acc[MI][NI];
    #pragma unroll
    for (int mi = 0; mi < MI; ++mi)
        #pragma unroll
        for (int ni = 0; ni < NI; ++ni)
            acc[mi][ni] = (f32x4){0.f, 0.f, 0.f, 0.f};

    const int bnn = tid & 63;
    const int bks = (tid >> 6) * 8;

    auto ISSUE = [&](short* ASP, short* BSP, int kk, f32x4* bF) {
        #pragma unroll
        for (int p = 0; p < PA; ++p) {
            const int slot = p * 256 + tid;
            const int row  = slot >> 2;
            const int seg  = (slot & 3) ^ ((row >> 1) & 3);
            GLD16(&A[(size_t)(m0 + row) * lda + kk + seg * 8],
                  &ASP[(p * 256 + wid * 64) * 8]);
        }
        if constexpr (BT) {
            #pragma unroll
            for (int p = 0; p < PB; ++p) {
                const int slot = p * 256 + tid;
                const int row  = slot >> 2;
                const int seg  = (slot & 3) ^ ((row >> 1) & 3);
                GLD16(&B[(size_t)(n0 + row) * ldb + kk + seg * 8],
                      &BSP[(p * 256 + wid * 64) * 8]);
            }
        } else {
            const int n_ = n0 + bnn;
            const bool nok_ = (!NBND) || (n_ < Ndim);
            #pragma unroll
            for (int j = 0; j < 8; ++j) {
                int k_ = kk + bks + j;
                bool ok_ = nok_ && ((!KBND) || (k_ < Kdim));
                bF[j >> 2][j & 3] = ok_ ? (float)B[(size_t)k_ * ldb + n_] : 0.f;
            }
        }
    };

    auto PACKB = [&](short* BSP, const f32x4* bF) {
        short8 w;
        #pragma unroll
        for (int j = 0; j < 8; ++j) w[j] = f2bf(bF[j >> 2][j & 3]);
        *reinterpret_cast<short8*>(&BSP[swz(bnn, bks)]) = w;
    };

    auto COMPUTE = [&](const short* ASP, const short* BSP) {
        const int ar = lane & 15;
        const int ac = (lane >> 4) * 8;
        short8 af[MI], bf[NI];
        #pragma unroll
        for (int mi = 0; mi < MI; ++mi)
            af[mi] = *reinterpret_cast<const short8*>(&ASP[swz(wm * WMT + mi * 16 + ar, ac)]);
        #pragma unroll
        for (int ni = 0; ni < NI; ++ni)
            bf[ni] = *reinterpret_cast<const short8*>(&BSP[swz(wn * WNT + ni * 16 + ar, ac)]);
        #pragma unroll
        for (int mi = 0; mi < MI; ++mi)
            #pragma unroll
            for (int ni = 0; ni < NI; ++ni)
                acc[mi][ni] = __builtin_amdgcn_mfma_f32_16x16x32_bf16(
                    af[mi], bf[ni], acc[mi][ni], 0, 0, 0);
    };

    const int Kloop = KBND ? ((Kdim + 31) & ~31) : Kdim;
    const int nt = Kloop / BK;   // even, >= 2

    f32x4 bF0[2], bF1[2];
    ISSUE(As0, Bs0, 0, bF0);
    if constexpr (!BT) PACKB(Bs0, bF0);
    __syncthreads();

    for (int t = 0; t < nt; t += 2) {
        ISSUE(As1, Bs1, (t + 1) * BK, bF1);
        COMPUTE(As0, Bs0);
        if constexpr (!BT) PACKB(Bs1, bF1);
        __syncthreads();

        const bool p2 = (t + 2 < nt);
        if (p2) ISSUE(As0, Bs0, (t + 2) * BK, bF0);
        COMPUTE(As1, Bs1);
        if (p2) { if constexpr (!BT) PACKB(Bs0, bF0); }
        __syncthreads();
    }

    #pragma unroll
    for (int mi = 0; mi < MI; ++mi) {
        #pragma unroll
        for (int ni = 0; ni < NI; ++ni) {
            const int n = n0 + wn * WNT + ni * 16 + (lane & 15);
            if (NBND && !PADW && n >= Ndim) continue;
            const int mbase = m0 + wm * WMT + mi * 16 + (lane >> 4) * 4;
            if constexpr (CT) {
                short4v sv;
                #pragma unroll
                for (int r = 0; r < 4; ++r) sv[r] = f2bf(acc[mi][ni][r]);
                *reinterpret_cast<short4v*>(&C[(size_t)n * ldc + mbase]) = sv;
            } else {
                #pragma unroll
                for (int r = 0; r < 4; ++r) {
                    float v = acc[mi][ni][r];
                    if (EPI == 1)      v = v / (1.f + __expf(-v));   // silu
                    else if (EPI == 2) v = v * aux[mbase + r];       // crcp
                    if constexpr (sizeof(TC) == 2) C[(size_t)(mbase + r) * ldc + n] = f2bf(v);
                    else                           C[(size_t)(mbase + r) * ldc + n] = v;
                }
            }
        }
    }
}

// ---------------- named GEMM wrappers ----------------
// g1: K-split x8 (z = 0..7, K=1024 each; batch = z>>1). 1024 blocks, 128x128 tile.
__global__ __launch_bounds__(256) void g1_gemm(const short* A, const short* B, float* C) {
    gemm_body<128, 128, 0, false, false, true, false, false, short, float>(
        A, B, C, HID, 1024, BS, BS, HID, 1024L, 1024L, (long)ES * HID, nullptr);
}
__global__ __launch_bounds__(256) void g1f_gemm(const short* A, const float* B, float* C) {
    gemm_body<128, 64, 0, false, false, false, false, false, float, float>(
        A, B, C, HID, 1024, BS, HID, HID, 1024L, 1024L * HID, (long)ES * HID, nullptr);
}
__global__ __launch_bounds__(256) void g2_gemm(const short* A, const float* B, short* C) {
    gemm_body<128, 64, 1, true, false, false, false, true, float, short>(
        A, B, C, FFN, HID, HID, FFN, FFNP,
        (long)SLOT * HID, (long)HID * FFN, (long)SLOT * FFNP, nullptr);
}
__global__ __launch_bounds__(256) void g3_gemm(const short* A, const float* B, short* C) {
    gemm_body<64, 64, 0, false, true, false, true, false, float, short>(
        A, B, C, HID, FFN, FFNP, HID, ES,
        (long)SLOT * FFNP, (long)FFN * HID, (long)SLOT, nullptr);
}
// g4: BM=64 x BN=128 -> 1024 blocks, N-side intensity preserved.
__global__ __launch_bounds__(256) void g4_gemm(const short* A, const short* B, float* C,
                                               const float* crcp) {
    gemm_body<64, 128, 2, false, false, true, false, false, short, float>(
        A, B, C, HID, ES, ES, ES, HID, 0, 0, 0, crcp);
}

// ---------------- launch ----------------

extern "C" void kernel_launch(void* const* d_in, const int* in_sizes, int n_in,
                              void* d_out, int out_size, void* d_ws, size_t ws_size,
                              hipStream_t stream)
{
    const float* x      = (const float*)d_in[0];
    const float* logits = (const float*)d_in[1];   // [BS][ES]
    const float* w_up   = (const float*)d_in[2];   // [16][1024][2730]
    const float* w_down = (const float*)d_in[3];   // [16][2730][1024]
    float* y = (float*)d_out;

    float* wsf     = (float*)d_ws;
    float* drcp    = wsf;                               // 4*2048
    float* crcp    = wsf + 8192;                        // 8192
    float* rowpart = wsf + 16384;                       // 8192*32
    float* colpart = rowpart + (size_t)8192 * 32;       // 32*2048
    short* DT      = (short*)(colpart + (size_t)32 * 2048);  // [2048][8192] bf16
    short* CB      = DT + (size_t)ES * BS;              // [8192][2048] bf16
    float* part    = (float*)(CB + (size_t)BS * ES);    // [8][2048][1024] fp32
    short* xt      = (short*)(part + (size_t)8 * ES * HID); // [2048][1024] bf16
    short* h       = xt + (size_t)ES * HID;             // [16][128][2752] bf16
    short* eoutT   = h + (size_t)NEXP * SLOT * FFNP;    // [1024][2048] bf16
    short* xT      = eoutT + (size_t)HID * ES;          // [1024][8192] bf16
    const size_t need_full = (size_t)((char*)(xT + (size_t)HID * BS) - (char*)d_ws);
    const bool use_bt = ws_size >= need_full;

    // NOTE: no memset. h pad columns (2730..2751) written as exact zeros by g2 (PADW).

    exp_stats_kernel<<<1024, 256, 0, stream>>>(logits, DT, CB, rowpart, colpart);
    rrow_kernel<<<32, 256, 0, stream>>>(rowpart, crcp);
    rcol_kernel<<<32, 256, 0, stream>>>(colpart, drcp);

    // G1: part[z] = expDT[:, z*1024:...] @ x[z*1024:...]   (K-split x8, nt=32, 1024 blocks)
    if (use_bt) {
        transpose_x<<<dim3(128, 16, 1), 256, 0, stream>>>(x, xT);
        g1_gemm<<<dim3(16, 8, 8), 256, 0, stream>>>(DT, xT, part);
    } else {
        g1f_gemm<<<dim3(16, 16, 8), 256, 0, stream>>>(DT, x, part);
    }

    // xt = bf16(sum_z drcp[z>>1] * part[z])
    reduce_xt<<<2048, 256, 0, stream>>>(part, drcp, xt);

    // G2: h[e] = silu(xt_e @ w_up_e), pad cols written as 0   (nt=32)
    g2_gemm<<<dim3(1, 43, NEXP), 256, 0, stream>>>(xt, w_up, h);

    // G3: eoutT = (h_e @ w_down_e)^T   (nt=86)
    g3_gemm<<<dim3(2, 16, NEXP), 256, 0, stream>>>(h, w_down, eoutT);

    // G4: y = expCB @ eout, row-scaled by crcp   (BM=64, nt=64, 1024 blocks)
    g4_gemm<<<dim3(128, 8, 1), 256, 0, stream>>>(CB, eoutT, y, crcp);
}

// Round 12
// 324.209 us; speedup vs baseline: 1.0984x; 1.0984x over previous
//
#include <hip/hip_runtime.h>
#include <hip/hip_bf16.h>
#include <math.h>

#define BS   8192   // batch*seq tokens
#define SEQQ 2048
#define HID  1024
#define ES   2048   // n_exp * slots
#define FFN  2730
#define FFNP 2752   // FFN padded to multiple of 32
#define NEXP 16
#define SLOT 128

typedef __attribute__((ext_vector_type(4))) float  f32x4;
typedef __attribute__((ext_vector_type(8))) short  short8;
typedef __attribute__((ext_vector_type(4))) short  short4v;

__device__ __forceinline__ short f2bf(float f) {
    union { float f; unsigned u; } v; v.f = f;
    unsigned r = v.u + 0x7fffu + ((v.u >> 16) & 1u);   // RNE
    return (short)(r >> 16);
}

// GEMM LDS swizzle (shorts). Row = 32 shorts, slot' = slot ^ ((row>>1)&3).
// Verified conflict-free rounds 4-11 (SQ_LDS_BANK_CONFLICT == 0).
__device__ __forceinline__ int swz(int row, int kk) {
    return (row << 5) + ((((kk >> 3) ^ (row >> 1)) & 3) << 3) + (kk & 7);
}

#define GLD16(gp, lp)                                                   \
    __builtin_amdgcn_global_load_lds(                                   \
        (__attribute__((address_space(1))) void*)(gp),                  \
        (__attribute__((address_space(3))) void*)(lp), 16, 0, 0)

// Transpose-tile swizzle for 64es x 256tok LDS tiles (see round 7).
__device__ __forceinline__ int tsw(int e) { return ((e >> 3) ^ e) & 7; }

// ---------- fused prep: exp(logits) -> DT [ES][BS] + CB [BS][ES] + sum partials ----------
__global__ __launch_bounds__(256) void exp_stats_kernel(const float* __restrict__ L,
                                                        short* __restrict__ DT,
                                                        short* __restrict__ CB,
                                                        float* __restrict__ rowpart,
                                                        float* __restrict__ colpart)
{
    const int t0 = (blockIdx.x & 31) << 8;       // 256-token tile
    const int et = blockIdx.x >> 5;              // es tile 0..31
    const int e0 = et << 6;                      // 64-es tile
    const int tid = threadIdx.x;
    const int lane = tid & 63;
    const int row = tid >> 3;                    // 0..31
    const int seg = tid & 7;                     // 0..7

    __shared__ short T[64 * 256];
    __shared__ float CP[4][64];

    float colacc[8];
    #pragma unroll
    for (int j = 0; j < 8; ++j) colacc[j] = 0.f;

    #pragma unroll
    for (int p = 0; p < 8; ++p) {
        const int tok = p * 32 + row;
        const float* src = L + (size_t)(t0 + tok) * ES + e0 + seg * 8;
        f32x4 a = *reinterpret_cast<const f32x4*>(src);
        f32x4 b = *reinterpret_cast<const f32x4*>(src + 4);
        float ex[8];
        #pragma unroll
        for (int j = 0; j < 4; ++j) ex[j]     = __expf(a[j]);
        #pragma unroll
        for (int j = 0; j < 4; ++j) ex[4 + j] = __expf(b[j]);
        float rs = 0.f;
        #pragma unroll
        for (int j = 0; j < 8; ++j) {
            const int e = seg * 8 + j;
            T[e * 256 + (tok ^ (((seg ^ j) & 7) << 3))] = f2bf(ex[j]);
            colacc[j] += ex[j];
            rs += ex[j];
        }
        rs += __shfl_xor(rs, 1, 64);
        rs += __shfl_xor(rs, 2, 64);
        rs += __shfl_xor(rs, 4, 64);
        if (seg == 0) rowpart[(size_t)(t0 + tok) * 32 + et] = rs;
    }
    #pragma unroll
    for (int j = 0; j < 8; ++j) {
        colacc[j] += __shfl_xor(colacc[j], 8, 64);
        colacc[j] += __shfl_xor(colacc[j], 16, 64);
        colacc[j] += __shfl_xor(colacc[j], 32, 64);
    }
    if ((lane >> 3) == 0) {
        #pragma unroll
        for (int j = 0; j < 8; ++j) CP[tid >> 6][(lane & 7) * 8 + j] = colacc[j];
    }
    __syncthreads();
    if (tid < 64)
        colpart[(size_t)(t0 >> 8) * ES + e0 + tid] =
            CP[0][tid] + CP[1][tid] + CP[2][tid] + CP[3][tid];
    // DT write-out (tok-contiguous 16B chunks per es row)
    {
        const int e = tid >> 2, ts = tid & 3;
        const int sw = tsw(e) << 3;
        const size_t o = (size_t)(e0 + e) * BS + t0 + ts * 64;
        #pragma unroll
        for (int q = 0; q < 8; ++q) {
            short8 w = *reinterpret_cast<const short8*>(&T[e * 256 + ((ts * 64 + q * 8) ^ sw)]);
            *reinterpret_cast<short8*>(&DT[o + q * 8]) = w;
        }
    }
    // CB write-out (es-contiguous 16B chunks per token)
    {
        #pragma unroll
        for (int p = 0; p < 8; ++p) {
            const int tok = p * 32 + row;
            short8 w;
            #pragma unroll
            for (int j = 0; j < 8; ++j) {
                const int e = seg * 8 + j;
                w[j] = T[e * 256 + (tok ^ (((seg ^ j) & 7) << 3))];
            }
            *reinterpret_cast<short8*>(&CB[(size_t)(t0 + tok) * ES + e0 + seg * 8]) = w;
        }
    }
}

__global__ __launch_bounds__(256) void rrow_kernel(const float* __restrict__ rowpart,
                                                   float* __restrict__ crcp)
{
    const int t = blockIdx.x * 256 + threadIdx.x;
    const float* p = rowpart + (size_t)t * 32;
    float s = 0.f;
    #pragma unroll
    for (int j = 0; j < 8; ++j) {
        f32x4 v = *reinterpret_cast<const f32x4*>(p + 4 * j);
        s += (v[0] + v[1]) + (v[2] + v[3]);
    }
    crcp[t] = 1.f / s;
}

__global__ __launch_bounds__(256) void rcol_kernel(const float* __restrict__ colpart,
                                                   float* __restrict__ drcp)
{
    const int g = blockIdx.x * 256 + threadIdx.x;   // b*2048 + c
    const int b = g >> 11, c = g & 2047;
    float s = 0.f;
    #pragma unroll
    for (int ch = 0; ch < 8; ++ch)
        s += colpart[(size_t)(b * 8 + ch) * ES + c];
    drcp[g] = 1.f / s;
}

// ---------- x fp32 [8192][1024] -> xT bf16 [1024][8192] ----------
__global__ __launch_bounds__(256) void transpose_x(const float* __restrict__ X,
                                                   short* __restrict__ XT)
{
    __shared__ short T[64][72];
    const int tid = threadIdx.x;
    const int k0 = blockIdx.x * 64;
    const int n0 = blockIdx.y * 64;
    {
        const int kk = tid >> 2;
        const int nn = (tid & 3) * 16;
        const float* src = X + (size_t)(k0 + kk) * HID + n0 + nn;
        #pragma unroll
        for (int j = 0; j < 4; ++j) {
            f32x4 v = *reinterpret_cast<const f32x4*>(src + 4 * j);
            short4v s;
            #pragma unroll
            for (int i = 0; i < 4; ++i) s[i] = f2bf(v[i]);
            *reinterpret_cast<short4v*>(&T[kk][nn + 4 * j]) = s;
        }
    }
    __syncthreads();
    {
        const int nn  = tid >> 2;
        const int kk4 = (tid & 3) * 16;
        short8 w0, w1;
        #pragma unroll
        for (int i = 0; i < 8; ++i) w0[i] = T[kk4 + i][nn];
        #pragma unroll
        for (int i = 0; i < 8; ++i) w1[i] = T[kk4 + 8 + i][nn];
        size_t o = (size_t)(n0 + nn) * BS + k0 + kk4;
        *reinterpret_cast<short8*>(&XT[o])     = w0;
        *reinterpret_cast<short8*>(&XT[o + 8]) = w1;
    }
}

// ---------- xt = bf16(sum_z drcp[z][c] * part[z][c][h]) (z = batch, 4 splits) ----------
__global__ __launch_bounds__(256) void reduce_xt(const float* __restrict__ P,
                                                 const float* __restrict__ drcp,
                                                 short* __restrict__ xt)
{
    const size_t i = ((size_t)blockIdx.x * 256 + threadIdx.x) * 4;
    const int c = (int)(i >> 10);
    const size_t CH = (size_t)ES * HID;
    f32x4 s0 = *reinterpret_cast<const f32x4*>(&P[i]);
    f32x4 s1 = *reinterpret_cast<const f32x4*>(&P[i + CH]);
    f32x4 s2 = *reinterpret_cast<const f32x4*>(&P[i + 2 * CH]);
    f32x4 s3 = *reinterpret_cast<const f32x4*>(&P[i + 3 * CH]);
    const float r0 = drcp[c], r1 = drcp[ES + c], r2 = drcp[2 * ES + c], r3 = drcp[3 * ES + c];
    short4v o;
    #pragma unroll
    for (int j = 0; j < 4; ++j)
        o[j] = f2bf((s0[j] * r0 + s1[j] * r1) + (s2[j] * r2 + s3[j] * r3));
    *reinterpret_cast<short4v*>(&xt[i]) = o;
}

// ---------------- bf16 MFMA GEMM body ----------------
// gload_lds A (+B if BT) dbuf, 1 barrier/step; float-B path: DEPTH-2 reg prefetch.
// EPI: 0 none, 1 silu, 2 row-scale by aux[m].
// PADW: store n >= Ndim too (acc==0 there since B staged 0).
template<int BM, int BN, int EPI, bool NBND, bool KBND, bool BT, bool CT, bool PADW,
         typename TB, typename TC>
__device__ __forceinline__
void gemm_body(const short* __restrict__ A, const TB* __restrict__ B,
               TC* __restrict__ C, int Ndim, int Kdim,
               int lda, int ldb, int ldc,
               long sA, long sB, long sC, const float* __restrict__ aux)
{
    constexpr int BK = 32;
    A += (size_t)blockIdx.z * sA;
    B += (size_t)blockIdx.z * sB;
    C += (size_t)blockIdx.z * sC;
    const int m0 = blockIdx.x * BM;
    const int n0 = blockIdx.y * BN;
    const int tid  = threadIdx.x;
    const int lane = tid & 63;
    const int wid  = tid >> 6;
    const int wm = wid >> 1, wn = wid & 1;
    constexpr int WMT = BM / 2, WNT = BN / 2, MI = WMT / 16, NI = WNT / 16;
    constexpr int PA = BM / 64;
    constexpr int PB = BN / 64;

    __shared__ __align__(16) short As0[BM * 32], As1[BM * 32];
    __shared__ __align__(16) short Bs0[BN * 32], Bs1[BN * 32];

    f32x4 acc[MI][NI];
    #pragma unroll
    for (int mi = 0; mi < MI; ++mi)
        #pragma unroll
        for (int ni = 0; ni < NI; ++ni)
            acc[mi][ni] = (f32x4){0.f, 0.f, 0.f, 0.f};

    const int bnn = tid & 63;
    const int bks = (tid >> 6) * 8;

    // issue direct-to-LDS loads for A (and B when BT)
    auto ISSUEA = [&](short* ASP, short* BSP, int kk) {
        #pragma unroll
        for (int p = 0; p < PA; ++p) {
            const int slot = p * 256 + tid;
            const int row  = slot >> 2;
            const int seg  = (slot & 3) ^ ((row >> 1) & 3);
            GLD16(&A[(size_t)(m0 + row) * lda + kk + seg * 8],
                  &ASP[(p * 256 + wid * 64) * 8]);
        }
        if constexpr (BT) {
            #pragma unroll
            for (int p = 0; p < PB; ++p) {
                const int slot = p * 256 + tid;
                const int row  = slot >> 2;
                const int seg  = (slot & 3) ^ ((row >> 1) & 3);
                GLD16(&B[(size_t)(n0 + row) * ldb + kk + seg * 8],
                      &BSP[(p * 256 + wid * 64) * 8]);
            }
        }
    };

    // float-B: load 8 k-values into named regs (depth-2 pipelined)
    auto LOADB = [&](f32x4* bF, int kk) {
        const int n_ = n0 + bnn;
        const bool nok_ = (!NBND) || (n_ < Ndim);
        #pragma unroll
        for (int j = 0; j < 8; ++j) {
            int k_ = kk + bks + j;
            bool ok_ = nok_ && ((!KBND) || (k_ < Kdim));
            bF[j >> 2][j & 3] = ok_ ? (float)B[(size_t)k_ * ldb + n_] : 0.f;
        }
    };

    auto PACKB = [&](short* BSP, const f32x4* bF) {
        short8 w;
        #pragma unroll
        for (int j = 0; j < 8; ++j) w[j] = f2bf(bF[j >> 2][j & 3]);
        *reinterpret_cast<short8*>(&BSP[swz(bnn, bks)]) = w;
    };

    auto COMPUTE = [&](const short* ASP, const short* BSP) {
        const int ar = lane & 15;
        const int ac = (lane >> 4) * 8;
        short8 af[MI], bf[NI];
        #pragma unroll
        for (int mi = 0; mi < MI; ++mi)
            af[mi] = *reinterpret_cast<const short8*>(&ASP[swz(wm * WMT + mi * 16 + ar, ac)]);
        #pragma unroll
        for (int ni = 0; ni < NI; ++ni)
            bf[ni] = *reinterpret_cast<const short8*>(&BSP[swz(wn * WNT + ni * 16 + ar, ac)]);
        #pragma unroll
        for (int mi = 0; mi < MI; ++mi)
            #pragma unroll
            for (int ni = 0; ni < NI; ++ni)
                acc[mi][ni] = __builtin_amdgcn_mfma_f32_16x16x32_bf16(
                    af[mi], bf[ni], acc[mi][ni], 0, 0, 0);
    };

    const int Kloop = KBND ? ((Kdim + 31) & ~31) : Kdim;
    const int nt = Kloop / BK;   // even, >= 2

    f32x4 bFa[2], bFb[2];        // named reg sets for even/odd tiles (depth-2)
    if constexpr (!BT) { LOADB(bFa, 0); LOADB(bFb, BK); }
    ISSUEA(As0, Bs0, 0);
    if constexpr (!BT) PACKB(Bs0, bFa);
    __syncthreads();

    for (int t = 0; t < nt; t += 2) {
        const bool p2 = (t + 2 < nt);
        const bool p3 = (t + 3 < nt);
        ISSUEA(As1, Bs1, (t + 1) * BK);
        if constexpr (!BT) { if (p2) LOADB(bFa, (t + 2) * BK); }
        COMPUTE(As0, Bs0);
        if constexpr (!BT) PACKB(Bs1, bFb);      // regs loaded 2 phases ago
        __syncthreads();

        if (p2) ISSUEA(As0, Bs0, (t + 2) * BK);
        if constexpr (!BT) { if (p3) LOADB(bFb, (t + 3) * BK); }
        COMPUTE(As1, Bs1);
        if constexpr (!BT) { if (p2) PACKB(Bs0, bFa); }
        __syncthreads();
    }

    #pragma unroll
    for (int mi = 0; mi < MI; ++mi) {
        #pragma unroll
        for (int ni = 0; ni < NI; ++ni) {
            const int n = n0 + wn * WNT + ni * 16 + (lane & 15);
            if (NBND && !PADW && n >= Ndim) continue;
            const int mbase = m0 + wm * WMT + mi * 16 + (lane >> 4) * 4;
            if constexpr (CT) {
                short4v sv;
                #pragma unroll
                for (int r = 0; r < 4; ++r) sv[r] = f2bf(acc[mi][ni][r]);
                *reinterpret_cast<short4v*>(&C[(size_t)n * ldc + mbase]) = sv;
            } else {
                #pragma unroll
                for (int r = 0; r < 4; ++r) {
                    float v = acc[mi][ni][r];
                    if (EPI == 1)      v = v / (1.f + __expf(-v));   // silu
                    else if (EPI == 2) v = v * aux[mbase + r];       // crcp
                    if constexpr (sizeof(TC) == 2) C[(size_t)(mbase + r) * ldc + n] = f2bf(v);
                    else                           C[(size_t)(mbase + r) * ldc + n] = v;
                }
            }
        }
    }
}

// ---------------- named GEMM wrappers (round-8 tiles/grids) ----------------
__global__ __launch_bounds__(256) void g1_gemm(const short* A, const short* B, float* C) {
    gemm_body<128, 128, 0, false, false, true, false, false, short, float>(
        A, B, C, HID, 2048, BS, BS, HID, 2048L, 2048L, (long)ES * HID, nullptr);
}
__global__ __launch_bounds__(256) void g1f_gemm(const short* A, const float* B, float* C) {
    gemm_body<128, 64, 0, false, false, false, false, false, float, float>(
        A, B, C, HID, 2048, BS, HID, HID, 2048L, 2048L * HID, (long)ES * HID, nullptr);
}
__global__ __launch_bounds__(256) void g2_gemm(const short* A, const float* B, short* C) {
    gemm_body<128, 64, 1, true, false, false, false, true, float, short>(
        A, B, C, FFN, HID, HID, FFN, FFNP,
        (long)SLOT * HID, (long)HID * FFN, (long)SLOT * FFNP, nullptr);
}
__global__ __launch_bounds__(256) void g3_gemm(const short* A, const float* B, short* C) {
    gemm_body<64, 64, 0, false, true, false, true, false, float, short>(
        A, B, C, HID, FFN, FFNP, HID, ES,
        (long)SLOT * FFNP, (long)FFN * HID, (long)SLOT, nullptr);
}
__global__ __launch_bounds__(256) void g4_gemm(const short* A, const short* B, float* C,
                                               const float* crcp) {
    gemm_body<128, 128, 2, false, false, true, false, false, short, float>(
        A, B, C, HID, ES, ES, ES, HID, 0, 0, 0, crcp);
}

// ---------------- launch ----------------

extern "C" void kernel_launch(void* const* d_in, const int* in_sizes, int n_in,
                              void* d_out, int out_size, void* d_ws, size_t ws_size,
                              hipStream_t stream)
{
    const float* x      = (const float*)d_in[0];
    const float* logits = (const float*)d_in[1];   // [BS][ES]
    const float* w_up   = (const float*)d_in[2];   // [16][1024][2730]
    const float* w_down = (const float*)d_in[3];   // [16][2730][1024]
    float* y = (float*)d_out;

    float* wsf     = (float*)d_ws;
    float* drcp    = wsf;                               // 4*2048
    float* crcp    = wsf + 8192;                        // 8192
    float* rowpart = wsf + 16384;                       // 8192*32
    float* colpart = rowpart + (size_t)8192 * 32;       // 32*2048
    short* DT      = (short*)(colpart + (size_t)32 * 2048);  // [2048][8192] bf16
    short* CB      = DT + (size_t)ES * BS;              // [8192][2048] bf16
    float* part    = (float*)(CB + (size_t)BS * ES);    // [4][2048][1024] fp32
    short* xt      = (short*)(part + (size_t)4 * ES * HID); // [2048][1024] bf16
    short* h       = xt + (size_t)ES * HID;             // [16][128][2752] bf16
    short* eoutT   = h + (size_t)NEXP * SLOT * FFNP;    // [1024][2048] bf16
    short* xT      = eoutT + (size_t)HID * ES;          // [1024][8192] bf16
    const size_t need_full = (size_t)((char*)(xT + (size_t)HID * BS) - (char*)d_ws);
    const bool use_bt = ws_size >= need_full;

    // NOTE: no memset. h pad columns (2730..2751) written as exact zeros by g2 (PADW).

    exp_stats_kernel<<<1024, 256, 0, stream>>>(logits, DT, CB, rowpart, colpart);
    rrow_kernel<<<32, 256, 0, stream>>>(rowpart, crcp);
    rcol_kernel<<<32, 256, 0, stream>>>(colpart, drcp);

    // G1: part[z] = expDT[:, batch z] @ x[batch z]   (K-split = batch x4, nt=64)
    if (use_bt) {
        transpose_x<<<dim3(128, 16, 1), 256, 0, stream>>>(x, xT);
        g1_gemm<<<dim3(16, 8, 4), 256, 0, stream>>>(DT, xT, part);
    } else {
        g1f_gemm<<<dim3(16, 16, 4), 256, 0, stream>>>(DT, x, part);
    }

    // xt = bf16(sum_z drcp[z] * part[z])
    reduce_xt<<<2048, 256, 0, stream>>>(part, drcp, xt);

    // G2: h[e] = silu(xt_e @ w_up_e), pad cols written as 0   (nt=32)
    g2_gemm<<<dim3(1, 43, NEXP), 256, 0, stream>>>(xt, w_up, h);

    // G3: eoutT = (h_e @ w_down_e)^T   (nt=86)
    g3_gemm<<<dim3(2, 16, NEXP), 256, 0, stream>>>(h, w_down, eoutT);

    // G4: y = expCB @ eout, row-scaled by crcp   (nt=64)
    g4_gemm<<<dim3(64, 8, 1), 256, 0, stream>>>(CB, eoutT, y, crcp);
}

// Round 13
// 321.119 us; speedup vs baseline: 1.1090x; 1.0096x over previous
//
#include <hip/hip_runtime.h>
#include <hip/hip_bf16.h>
#include <math.h>

#define BS   8192   // batch*seq tokens
#define SEQQ 2048
#define HID  1024
#define ES   2048   // n_exp * slots
#define FFN  2730
#define FFNP 2752   // FFN padded to multiple of 32
#define NEXP 16
#define SLOT 128

typedef __attribute__((ext_vector_type(4))) float  f32x4;
typedef __attribute__((ext_vector_type(8))) short  short8;
typedef __attribute__((ext_vector_type(4))) short  short4v;

__device__ __forceinline__ short f2bf(float f) {
    union { float f; unsigned u; } v; v.f = f;
    unsigned r = v.u + 0x7fffu + ((v.u >> 16) & 1u);   // RNE
    return (short)(r >> 16);
}

// GEMM LDS swizzle (shorts). Row = 32 shorts, slot' = slot ^ ((row>>1)&3).
// Verified conflict-free rounds 4-12 (SQ_LDS_BANK_CONFLICT == 0).
__device__ __forceinline__ int swz(int row, int kk) {
    return (row << 5) + ((((kk >> 3) ^ (row >> 1)) & 3) << 3) + (kk & 7);
}

#define GLD16(gp, lp)                                                   \
    __builtin_amdgcn_global_load_lds(                                   \
        (__attribute__((address_space(1))) void*)(gp),                  \
        (__attribute__((address_space(3))) void*)(lp), 16, 0, 0)

// Transpose-tile swizzle for 64es x 256tok LDS tiles (see round 7).
__device__ __forceinline__ int tsw(int e) { return ((e >> 3) ^ e) & 7; }

// ---------- fused prep: exp(logits) -> DT [ES][BS] + CB [BS][ES] + sum partials ----------
__global__ __launch_bounds__(256) void exp_stats_kernel(const float* __restrict__ L,
                                                        short* __restrict__ DT,
                                                        short* __restrict__ CB,
                                                        float* __restrict__ rowpart,
                                                        float* __restrict__ colpart)
{
    const int t0 = (blockIdx.x & 31) << 8;       // 256-token tile
    const int et = blockIdx.x >> 5;              // es tile 0..31
    const int e0 = et << 6;                      // 64-es tile
    const int tid = threadIdx.x;
    const int lane = tid & 63;
    const int row = tid >> 3;                    // 0..31
    const int seg = tid & 7;                     // 0..7

    __shared__ short T[64 * 256];
    __shared__ float CP[4][64];

    float colacc[8];
    #pragma unroll
    for (int j = 0; j < 8; ++j) colacc[j] = 0.f;

    #pragma unroll
    for (int p = 0; p < 8; ++p) {
        const int tok = p * 32 + row;
        const float* src = L + (size_t)(t0 + tok) * ES + e0 + seg * 8;
        f32x4 a = *reinterpret_cast<const f32x4*>(src);
        f32x4 b = *reinterpret_cast<const f32x4*>(src + 4);
        float ex[8];
        #pragma unroll
        for (int j = 0; j < 4; ++j) ex[j]     = __expf(a[j]);
        #pragma unroll
        for (int j = 0; j < 4; ++j) ex[4 + j] = __expf(b[j]);
        float rs = 0.f;
        #pragma unroll
        for (int j = 0; j < 8; ++j) {
            const int e = seg * 8 + j;
            T[e * 256 + (tok ^ (((seg ^ j) & 7) << 3))] = f2bf(ex[j]);
            colacc[j] += ex[j];
            rs += ex[j];
        }
        rs += __shfl_xor(rs, 1, 64);
        rs += __shfl_xor(rs, 2, 64);
        rs += __shfl_xor(rs, 4, 64);
        if (seg == 0) rowpart[(size_t)(t0 + tok) * 32 + et] = rs;
    }
    #pragma unroll
    for (int j = 0; j < 8; ++j) {
        colacc[j] += __shfl_xor(colacc[j], 8, 64);
        colacc[j] += __shfl_xor(colacc[j], 16, 64);
        colacc[j] += __shfl_xor(colacc[j], 32, 64);
    }
    if ((lane >> 3) == 0) {
        #pragma unroll
        for (int j = 0; j < 8; ++j) CP[tid >> 6][(lane & 7) * 8 + j] = colacc[j];
    }
    __syncthreads();
    if (tid < 64)
        colpart[(size_t)(t0 >> 8) * ES + e0 + tid] =
            CP[0][tid] + CP[1][tid] + CP[2][tid] + CP[3][tid];
    // DT write-out (tok-contiguous 16B chunks per es row)
    {
        const int e = tid >> 2, ts = tid & 3;
        const int sw = tsw(e) << 3;
        const size_t o = (size_t)(e0 + e) * BS + t0 + ts * 64;
        #pragma unroll
        for (int q = 0; q < 8; ++q) {
            short8 w = *reinterpret_cast<const short8*>(&T[e * 256 + ((ts * 64 + q * 8) ^ sw)]);
            *reinterpret_cast<short8*>(&DT[o + q * 8]) = w;
        }
    }
    // CB write-out (es-contiguous 16B chunks per token)
    {
        #pragma unroll
        for (int p = 0; p < 8; ++p) {
            const int tok = p * 32 + row;
            short8 w;
            #pragma unroll
            for (int j = 0; j < 8; ++j) {
                const int e = seg * 8 + j;
                w[j] = T[e * 256 + (tok ^ (((seg ^ j) & 7) << 3))];
            }
            *reinterpret_cast<short8*>(&CB[(size_t)(t0 + tok) * ES + e0 + seg * 8]) = w;
        }
    }
}

__global__ __launch_bounds__(256) void rrow_kernel(const float* __restrict__ rowpart,
                                                   float* __restrict__ crcp)
{
    const int t = blockIdx.x * 256 + threadIdx.x;
    const float* p = rowpart + (size_t)t * 32;
    float s = 0.f;
    #pragma unroll
    for (int j = 0; j < 8; ++j) {
        f32x4 v = *reinterpret_cast<const f32x4*>(p + 4 * j);
        s += (v[0] + v[1]) + (v[2] + v[3]);
    }
    crcp[t] = 1.f / s;
}

__global__ __launch_bounds__(256) void rcol_kernel(const float* __restrict__ colpart,
                                                   float* __restrict__ drcp)
{
    const int g = blockIdx.x * 256 + threadIdx.x;   // b*2048 + c
    const int b = g >> 11, c = g & 2047;
    float s = 0.f;
    #pragma unroll
    for (int ch = 0; ch < 8; ++ch)
        s += colpart[(size_t)(b * 8 + ch) * ES + c];
    drcp[g] = 1.f / s;
}

// ---------- x fp32 [8192][1024] -> xT bf16 [1024][8192] ----------
__global__ __launch_bounds__(256) void transpose_x(const float* __restrict__ X,
                                                   short* __restrict__ XT)
{
    __shared__ short T[64][72];
    const int tid = threadIdx.x;
    const int k0 = blockIdx.x * 64;
    const int n0 = blockIdx.y * 64;
    {
        const int kk = tid >> 2;
        const int nn = (tid & 3) * 16;
        const float* src = X + (size_t)(k0 + kk) * HID + n0 + nn;
        #pragma unroll
        for (int j = 0; j < 4; ++j) {
            f32x4 v = *reinterpret_cast<const f32x4*>(src + 4 * j);
            short4v s;
            #pragma unroll
            for (int i = 0; i < 4; ++i) s[i] = f2bf(v[i]);
            *reinterpret_cast<short4v*>(&T[kk][nn + 4 * j]) = s;
        }
    }
    __syncthreads();
    {
        const int nn  = tid >> 2;
        const int kk4 = (tid & 3) * 16;
        short8 w0, w1;
        #pragma unroll
        for (int i = 0; i < 8; ++i) w0[i] = T[kk4 + i][nn];
        #pragma unroll
        for (int i = 0; i < 8; ++i) w1[i] = T[kk4 + 8 + i][nn];
        size_t o = (size_t)(n0 + nn) * BS + k0 + kk4;
        *reinterpret_cast<short8*>(&XT[o])     = w0;
        *reinterpret_cast<short8*>(&XT[o + 8]) = w1;
    }
}

// ---------- xt = bf16(sum_z drcp[z][c] * part[z][c][h]) (z = batch, 4 splits) ----------
__global__ __launch_bounds__(256) void reduce_xt(const float* __restrict__ P,
                                                 const float* __restrict__ drcp,
                                                 short* __restrict__ xt)
{
    const size_t i = ((size_t)blockIdx.x * 256 + threadIdx.x) * 4;
    const int c = (int)(i >> 10);
    const size_t CH = (size_t)ES * HID;
    f32x4 s0 = *reinterpret_cast<const f32x4*>(&P[i]);
    f32x4 s1 = *reinterpret_cast<const f32x4*>(&P[i + CH]);
    f32x4 s2 = *reinterpret_cast<const f32x4*>(&P[i + 2 * CH]);
    f32x4 s3 = *reinterpret_cast<const f32x4*>(&P[i + 3 * CH]);
    const float r0 = drcp[c], r1 = drcp[ES + c], r2 = drcp[2 * ES + c], r3 = drcp[3 * ES + c];
    short4v o;
    #pragma unroll
    for (int j = 0; j < 4; ++j)
        o[j] = f2bf((s0[j] * r0 + s1[j] * r1) + (s2[j] * r2 + s3[j] * r3));
    *reinterpret_cast<short4v*>(&xt[i]) = o;
}

// ---------------- bf16 MFMA GEMM body ----------------
// BT path: gload_lds A+B dbuf, __syncthreads (round-8 proven).
// float-B path: counted-vmcnt RAW-barrier schedule (T3/T4-lite): B regs stay in
//   flight ACROSS barriers (syncthreads would drain vmcnt to 0 and defeat depth-2).
// EPI: 0 none, 1 silu, 2 row-scale by aux[m].
// PADW: store n >= Ndim too (acc==0 there since B staged 0).
template<int BM, int BN, int EPI, bool NBND, bool KBND, bool BT, bool CT, bool PADW,
         typename TB, typename TC>
__device__ __forceinline__
void gemm_body(const short* __restrict__ A, const TB* __restrict__ B,
               TC* __restrict__ C, int Ndim, int Kdim,
               int lda, int ldb, int ldc,
               long sA, long sB, long sC, const float* __restrict__ aux)
{
    constexpr int BK = 32;
    A += (size_t)blockIdx.z * sA;
    B += (size_t)blockIdx.z * sB;
    C += (size_t)blockIdx.z * sC;
    const int m0 = blockIdx.x * BM;
    const int n0 = blockIdx.y * BN;
    const int tid  = threadIdx.x;
    const int lane = tid & 63;
    const int wid  = tid >> 6;
    const int wm = wid >> 1, wn = wid & 1;
    constexpr int WMT = BM / 2, WNT = BN / 2, MI = WMT / 16, NI = WNT / 16;
    constexpr int PA = BM / 64;
    constexpr int PB = BN / 64;

    __shared__ __align__(16) short As0[BM * 32], As1[BM * 32];
    __shared__ __align__(16) short Bs0[BN * 32], Bs1[BN * 32];

    f32x4 acc[MI][NI];
    #pragma unroll
    for (int mi = 0; mi < MI; ++mi)
        #pragma unroll
        for (int ni = 0; ni < NI; ++ni)
            acc[mi][ni] = (f32x4){0.f, 0.f, 0.f, 0.f};

    const int bnn = tid & 63;
    const int bks = (tid >> 6) * 8;

    // issue direct-to-LDS loads for A (and B when BT)
    auto ISSUEA = [&](short* ASP, short* BSP, int kk) {
        #pragma unroll
        for (int p = 0; p < PA; ++p) {
            const int slot = p * 256 + tid;
            const int row  = slot >> 2;
            const int seg  = (slot & 3) ^ ((row >> 1) & 3);
            GLD16(&A[(size_t)(m0 + row) * lda + kk + seg * 8],
                  &ASP[(p * 256 + wid * 64) * 8]);
        }
        if constexpr (BT) {
            #pragma unroll
            for (int p = 0; p < PB; ++p) {
                const int slot = p * 256 + tid;
                const int row  = slot >> 2;
                const int seg  = (slot & 3) ^ ((row >> 1) & 3);
                GLD16(&B[(size_t)(n0 + row) * ldb + kk + seg * 8],
                      &BSP[(p * 256 + wid * 64) * 8]);
            }
        }
    };

    // float-B: load 8 k-values into named regs (exactly 8 vmem instructions)
    auto LOADB = [&](f32x4* bF, int kk) {
        const int n_ = n0 + bnn;
        const bool nok_ = (!NBND) || (n_ < Ndim);
        #pragma unroll
        for (int j = 0; j < 8; ++j) {
            int k_ = kk + bks + j;
            bool ok_ = nok_ && ((!KBND) || (k_ < Kdim));
            bF[j >> 2][j & 3] = ok_ ? (float)B[(size_t)k_ * ldb + n_] : 0.f;
        }
    };

    auto PACKB = [&](short* BSP, const f32x4* bF) {
        short8 w;
        #pragma unroll
        for (int j = 0; j < 8; ++j) w[j] = f2bf(bF[j >> 2][j & 3]);
        *reinterpret_cast<short8*>(&BSP[swz(bnn, bks)]) = w;
    };

    auto COMPUTE = [&](const short* ASP, const short* BSP) {
        const int ar = lane & 15;
        const int ac = (lane >> 4) * 8;
        short8 af[MI], bf[NI];
        #pragma unroll
        for (int mi = 0; mi < MI; ++mi)
            af[mi] = *reinterpret_cast<const short8*>(&ASP[swz(wm * WMT + mi * 16 + ar, ac)]);
        #pragma unroll
        for (int ni = 0; ni < NI; ++ni)
            bf[ni] = *reinterpret_cast<const short8*>(&BSP[swz(wn * WNT + ni * 16 + ar, ac)]);
        #pragma unroll
        for (int mi = 0; mi < MI; ++mi)
            #pragma unroll
            for (int ni = 0; ni < NI; ++ni)
                acc[mi][ni] = __builtin_amdgcn_mfma_f32_16x16x32_bf16(
                    af[mi], bf[ni], acc[mi][ni], 0, 0, 0);
    };

    const int Kloop = KBND ? ((Kdim + 31) & ~31) : Kdim;
    const int nt = Kloop / BK;   // even, >= 2

    if constexpr (BT) {
        // ---- round-8 proven dbuf loop (all-gload_lds operands, L2/L3-warm) ----
        ISSUEA(As0, Bs0, 0);
        __syncthreads();
        for (int t = 0; t < nt; t += 2) {
            ISSUEA(As1, Bs1, (t + 1) * BK);
            COMPUTE(As0, Bs0);
            __syncthreads();
            const bool p2 = (t + 2 < nt);
            if (p2) ISSUEA(As0, Bs0, (t + 2) * BK);
            COMPUTE(As1, Bs1);
            __syncthreads();
        }
    } else {
        // ---- counted-vmcnt raw-barrier schedule (weights stream from HBM) ----
        // Invariant at each barrier: only the 8 B-loads for tile t+2 remain in
        // flight (vmcnt(8)); A-GLD16s (issued BEFORE them, sched_barrier-pinned)
        // and all ds ops are drained.
        f32x4 bFa[2], bFb[2];
        LOADB(bFa, 0);
        __builtin_amdgcn_sched_barrier(0);
        ISSUEA(As0, Bs0, 0);
        __builtin_amdgcn_sched_barrier(0);
        LOADB(bFb, BK);
        PACKB(Bs0, bFa);                       // compiler auto-waits bFa only
        asm volatile("s_waitcnt vmcnt(8) lgkmcnt(0)" ::: "memory");
        __builtin_amdgcn_s_barrier();

        for (int t = 0; t < nt; t += 2) {
            // even step: compute tile t (As0/Bs0)
            {
                ISSUEA(As1, Bs1, (t + 1) * BK);          // t+1 < nt (nt even)
                __builtin_amdgcn_sched_barrier(0);
                const bool pf = (t + 2 < nt);
                if (pf) LOADB(bFa, (t + 2) * BK);
                COMPUTE(As0, Bs0);
                PACKB(Bs1, bFb);                          // regs loaded 2 phases ago
                if (pf) asm volatile("s_waitcnt vmcnt(8) lgkmcnt(0)" ::: "memory");
                else    asm volatile("s_waitcnt vmcnt(0) lgkmcnt(0)" ::: "memory");
                __builtin_amdgcn_s_barrier();
            }
            // odd step: compute tile t+1 (As1/Bs1)
            {
                const bool p2 = (t + 2 < nt);
                const bool p3 = (t + 3 < nt);
                if (p2) ISSUEA(As0, Bs0, (t + 2) * BK);
                __builtin_amdgcn_sched_barrier(0);
                if (p3) LOADB(bFb, (t + 3) * BK);
                COMPUTE(As1, Bs1);
                if (p2) PACKB(Bs0, bFa);
                if (p3) asm volatile("s_waitcnt vmcnt(8) lgkmcnt(0)" ::: "memory");
                else    asm volatile("s_waitcnt vmcnt(0) lgkmcnt(0)" ::: "memory");
                __builtin_amdgcn_s_barrier();
            }
        }
    }

    #pragma unroll
    for (int mi = 0; mi < MI; ++mi) {
        #pragma unroll
        for (int ni = 0; ni < NI; ++ni) {
            const int n = n0 + wn * WNT + ni * 16 + (lane & 15);
            if (NBND && !PADW && n >= Ndim) continue;
            const int mbase = m0 + wm * WMT + mi * 16 + (lane >> 4) * 4;
            if constexpr (CT) {
                short4v sv;
                #pragma unroll
                for (int r = 0; r < 4; ++r) sv[r] = f2bf(acc[mi][ni][r]);
                *reinterpret_cast<short4v*>(&C[(size_t)n * ldc + mbase]) = sv;
            } else {
                #pragma unroll
                for (int r = 0; r < 4; ++r) {
                    float v = acc[mi][ni][r];
                    if (EPI == 1)      v = v / (1.f + __expf(-v));   // silu
                    else if (EPI == 2) v = v * aux[mbase + r];       // crcp
                    if constexpr (sizeof(TC) == 2) C[(size_t)(mbase + r) * ldc + n] = f2bf(v);
                    else                           C[(size_t)(mbase + r) * ldc + n] = v;
                }
            }
        }
    }
}

// ---------------- named GEMM wrappers (round-8 tiles/grids) ----------------
__global__ __launch_bounds__(256) void g1_gemm(const short* A, const short* B, float* C) {
    gemm_body<128, 128, 0, false, false, true, false, false, short, float>(
        A, B, C, HID, 2048, BS, BS, HID, 2048L, 2048L, (long)ES * HID, nullptr);
}
__global__ __launch_bounds__(256) void g1f_gemm(const short* A, const float* B, float* C) {
    gemm_body<128, 64, 0, false, false, false, false, false, float, float>(
        A, B, C, HID, 2048, BS, HID, HID, 2048L, 2048L * HID, (long)ES * HID, nullptr);
}
__global__ __launch_bounds__(256) void g2_gemm(const short* A, const float* B, short* C) {
    gemm_body<128, 64, 1, true, false, false, false, true, float, short>(
        A, B, C, FFN, HID, HID, FFN, FFNP,
        (long)SLOT * HID, (long)HID * FFN, (long)SLOT * FFNP, nullptr);
}
__global__ __launch_bounds__(256) void g3_gemm(const short* A, const float* B, short* C) {
    gemm_body<64, 64, 0, false, true, false, true, false, float, short>(
        A, B, C, HID, FFN, FFNP, HID, ES,
        (long)SLOT * FFNP, (long)FFN * HID, (long)SLOT, nullptr);
}
__global__ __launch_bounds__(256) void g4_gemm(const short* A, const short* B, float* C,
                                               const float* crcp) {
    gemm_body<128, 128, 2, false, false, true, false, false, short, float>(
        A, B, C, HID, ES, ES, ES, HID, 0, 0, 0, crcp);
}

// ---------------- launch ----------------

extern "C" void kernel_launch(void* const* d_in, const int* in_sizes, int n_in,
                              void* d_out, int out_size, void* d_ws, size_t ws_size,
                              hipStream_t stream)
{
    const float* x      = (const float*)d_in[0];
    const float* logits = (const float*)d_in[1];   // [BS][ES]
    const float* w_up   = (const float*)d_in[2];   // [16][1024][2730]
    const float* w_down = (const float*)d_in[3];   // [16][2730][1024]
    float* y = (float*)d_out;

    float* wsf     = (float*)d_ws;
    float* drcp    = wsf;                               // 4*2048
    float* crcp    = wsf + 8192;                        // 8192
    float* rowpart = wsf + 16384;                       // 8192*32
    float* colpart = rowpart + (size_t)8192 * 32;       // 32*2048
    short* DT      = (short*)(colpart + (size_t)32 * 2048);  // [2048][8192] bf16
    short* CB      = DT + (size_t)ES * BS;              // [8192][2048] bf16
    float* part    = (float*)(CB + (size_t)BS * ES);    // [4][2048][1024] fp32
    short* xt      = (short*)(part + (size_t)4 * ES * HID); // [2048][1024] bf16
    short* h       = xt + (size_t)ES * HID;             // [16][128][2752] bf16
    short* eoutT   = h + (size_t)NEXP * SLOT * FFNP;    // [1024][2048] bf16
    short* xT      = eoutT + (size_t)HID * ES;          // [1024][8192] bf16
    const size_t need_full = (size_t)((char*)(xT + (size_t)HID * BS) - (char*)d_ws);
    const bool use_bt = ws_size >= need_full;

    // NOTE: no memset. h pad columns (2730..2751) written as exact zeros by g2 (PADW).

    exp_stats_kernel<<<1024, 256, 0, stream>>>(logits, DT, CB, rowpart, colpart);
    rrow_kernel<<<32, 256, 0, stream>>>(rowpart, crcp);
    rcol_kernel<<<32, 256, 0, stream>>>(colpart, drcp);

    // G1: part[z] = expDT[:, batch z] @ x[batch z]   (K-split = batch x4, nt=64)
    if (use_bt) {
        transpose_x<<<dim3(128, 16, 1), 256, 0, stream>>>(x, xT);
        g1_gemm<<<dim3(16, 8, 4), 256, 0, stream>>>(DT, xT, part);
    } else {
        g1f_gemm<<<dim3(16, 16, 4), 256, 0, stream>>>(DT, x, part);
    }

    // xt = bf16(sum_z drcp[z] * part[z])
    reduce_xt<<<2048, 256, 0, stream>>>(part, drcp, xt);

    // G2: h[e] = silu(xt_e @ w_up_e), pad cols written as 0   (nt=32)
    g2_gemm<<<dim3(1, 43, NEXP), 256, 0, stream>>>(xt, w_up, h);

    // G3: eoutT = (h_e @ w_down_e)^T   (nt=86)
    g3_gemm<<<dim3(2, 16, NEXP), 256, 0, stream>>>(h, w_down, eoutT);

    // G4: y = expCB @ eout, row-scaled by crcp   (nt=64)
    g4_gemm<<<dim3(64, 8, 1), 256, 0, stream>>>(CB, eoutT, y, crcp);
}

// Round 14
// 288.061 us; speedup vs baseline: 1.2363x; 1.1148x over previous
//
#include <hip/hip_runtime.h>
#include <hip/hip_bf16.h>
#include <math.h>

#define BS   8192   // batch*seq tokens
#define SEQQ 2048
#define HID  1024
#define ES   2048   // n_exp * slots
#define FFN  2730
#define FFNP 2752   // FFN padded to multiple of 32
#define NEXP 16
#define SLOT 128

typedef __attribute__((ext_vector_type(4))) float  f32x4;
typedef __attribute__((ext_vector_type(2))) float  f32x2;
typedef __attribute__((ext_vector_type(8))) short  short8;
typedef __attribute__((ext_vector_type(4))) short  short4v;

__device__ __forceinline__ short f2bf(float f) {
    union { float f; unsigned u; } v; v.f = f;
    unsigned r = v.u + 0x7fffu + ((v.u >> 16) & 1u);   // RNE
    return (short)(r >> 16);
}

// GEMM LDS swizzle (shorts). Row = 32 shorts, slot' = slot ^ ((row>>1)&3).
// Verified conflict-free for frag reads + 16B staging writes (rounds 4-13).
__device__ __forceinline__ int swz(int row, int kk) {
    return (row << 5) + ((((kk >> 3) ^ (row >> 1)) & 3) << 3) + (kk & 7);
}

#define GLD16(gp, lp)                                                   \
    __builtin_amdgcn_global_load_lds(                                   \
        (__attribute__((address_space(1))) void*)(gp),                  \
        (__attribute__((address_space(3))) void*)(lp), 16, 0, 0)

// Transpose-tile swizzle for 64es x 256tok LDS tiles (see round 7).
__device__ __forceinline__ int tsw(int e) { return ((e >> 3) ^ e) & 7; }

// ---------- fused prep: exp(logits) -> DT [ES][BS] + CB [BS][ES] + sum partials ----------
__global__ __launch_bounds__(256) void exp_stats_kernel(const float* __restrict__ L,
                                                        short* __restrict__ DT,
                                                        short* __restrict__ CB,
                                                        float* __restrict__ rowpart,
                                                        float* __restrict__ colpart)
{
    const int t0 = (blockIdx.x & 31) << 8;       // 256-token tile
    const int et = blockIdx.x >> 5;              // es tile 0..31
    const int e0 = et << 6;                      // 64-es tile
    const int tid = threadIdx.x;
    const int lane = tid & 63;
    const int row = tid >> 3;                    // 0..31
    const int seg = tid & 7;                     // 0..7

    __shared__ short T[64 * 256];
    __shared__ float CP[4][64];

    float colacc[8];
    #pragma unroll
    for (int j = 0; j < 8; ++j) colacc[j] = 0.f;

    #pragma unroll
    for (int p = 0; p < 8; ++p) {
        const int tok = p * 32 + row;
        const float* src = L + (size_t)(t0 + tok) * ES + e0 + seg * 8;
        f32x4 a = *reinterpret_cast<const f32x4*>(src);
        f32x4 b = *reinterpret_cast<const f32x4*>(src + 4);
        float ex[8];
        #pragma unroll
        for (int j = 0; j < 4; ++j) ex[j]     = __expf(a[j]);
        #pragma unroll
        for (int j = 0; j < 4; ++j) ex[4 + j] = __expf(b[j]);
        float rs = 0.f;
        #pragma unroll
        for (int j = 0; j < 8; ++j) {
            const int e = seg * 8 + j;
            T[e * 256 + (tok ^ (((seg ^ j) & 7) << 3))] = f2bf(ex[j]);
            colacc[j] += ex[j];
            rs += ex[j];
        }
        rs += __shfl_xor(rs, 1, 64);
        rs += __shfl_xor(rs, 2, 64);
        rs += __shfl_xor(rs, 4, 64);
        if (seg == 0) rowpart[(size_t)(t0 + tok) * 32 + et] = rs;
    }
    #pragma unroll
    for (int j = 0; j < 8; ++j) {
        colacc[j] += __shfl_xor(colacc[j], 8, 64);
        colacc[j] += __shfl_xor(colacc[j], 16, 64);
        colacc[j] += __shfl_xor(colacc[j], 32, 64);
    }
    if ((lane >> 3) == 0) {
        #pragma unroll
        for (int j = 0; j < 8; ++j) CP[tid >> 6][(lane & 7) * 8 + j] = colacc[j];
    }
    __syncthreads();
    if (tid < 64)
        colpart[(size_t)(t0 >> 8) * ES + e0 + tid] =
            CP[0][tid] + CP[1][tid] + CP[2][tid] + CP[3][tid];
    // DT write-out (tok-contiguous 16B chunks per es row)
    {
        const int e = tid >> 2, ts = tid & 3;
        const int sw = tsw(e) << 3;
        const size_t o = (size_t)(e0 + e) * BS + t0 + ts * 64;
        #pragma unroll
        for (int q = 0; q < 8; ++q) {
            short8 w = *reinterpret_cast<const short8*>(&T[e * 256 + ((ts * 64 + q * 8) ^ sw)]);
            *reinterpret_cast<short8*>(&DT[o + q * 8]) = w;
        }
    }
    // CB write-out (es-contiguous 16B chunks per token)
    {
        #pragma unroll
        for (int p = 0; p < 8; ++p) {
            const int tok = p * 32 + row;
            short8 w;
            #pragma unroll
            for (int j = 0; j < 8; ++j) {
                const int e = seg * 8 + j;
                w[j] = T[e * 256 + (tok ^ (((seg ^ j) & 7) << 3))];
            }
            *reinterpret_cast<short8*>(&CB[(size_t)(t0 + tok) * ES + e0 + seg * 8]) = w;
        }
    }
}

__global__ __launch_bounds__(256) void rrow_kernel(const float* __restrict__ rowpart,
                                                   float* __restrict__ crcp)
{
    const int t = blockIdx.x * 256 + threadIdx.x;
    const float* p = rowpart + (size_t)t * 32;
    float s = 0.f;
    #pragma unroll
    for (int j = 0; j < 8; ++j) {
        f32x4 v = *reinterpret_cast<const f32x4*>(p + 4 * j);
        s += (v[0] + v[1]) + (v[2] + v[3]);
    }
    crcp[t] = 1.f / s;
}

__global__ __launch_bounds__(256) void rcol_kernel(const float* __restrict__ colpart,
                                                   float* __restrict__ drcp)
{
    const int g = blockIdx.x * 256 + threadIdx.x;   // b*2048 + c
    const int b = g >> 11, c = g & 2047;
    float s = 0.f;
    #pragma unroll
    for (int ch = 0; ch < 8; ++ch)
        s += colpart[(size_t)(b * 8 + ch) * ES + c];
    drcp[g] = 1.f / s;
}

// ---------- x fp32 [8192][1024] -> xT bf16 [1024][8192] ----------
__global__ __launch_bounds__(256) void transpose_x(const float* __restrict__ X,
                                                   short* __restrict__ XT)
{
    __shared__ short T[64][72];
    const int tid = threadIdx.x;
    const int k0 = blockIdx.x * 64;
    const int n0 = blockIdx.y * 64;
    {
        const int kk = tid >> 2;
        const int nn = (tid & 3) * 16;
        const float* src = X + (size_t)(k0 + kk) * HID + n0 + nn;
        #pragma unroll
        for (int j = 0; j < 4; ++j) {
            f32x4 v = *reinterpret_cast<const f32x4*>(src + 4 * j);
            short4v s;
            #pragma unroll
            for (int i = 0; i < 4; ++i) s[i] = f2bf(v[i]);
            *reinterpret_cast<short4v*>(&T[kk][nn + 4 * j]) = s;
        }
    }
    __syncthreads();
    {
        const int nn  = tid >> 2;
        const int kk4 = (tid & 3) * 16;
        short8 w0, w1;
        #pragma unroll
        for (int i = 0; i < 8; ++i) w0[i] = T[kk4 + i][nn];
        #pragma unroll
        for (int i = 0; i < 8; ++i) w1[i] = T[kk4 + 8 + i][nn];
        size_t o = (size_t)(n0 + nn) * BS + k0 + kk4;
        *reinterpret_cast<short8*>(&XT[o])     = w0;
        *reinterpret_cast<short8*>(&XT[o + 8]) = w1;
    }
}

// ---------- xt = bf16(sum_z drcp[z][c] * part[z][c][h]) (z = batch, 4 splits) ----------
__global__ __launch_bounds__(256) void reduce_xt(const float* __restrict__ P,
                                                 const float* __restrict__ drcp,
                                                 short* __restrict__ xt)
{
    const size_t i = ((size_t)blockIdx.x * 256 + threadIdx.x) * 4;
    const int c = (int)(i >> 10);
    const size_t CH = (size_t)ES * HID;
    f32x4 s0 = *reinterpret_cast<const f32x4*>(&P[i]);
    f32x4 s1 = *reinterpret_cast<const f32x4*>(&P[i + CH]);
    f32x4 s2 = *reinterpret_cast<const f32x4*>(&P[i + 2 * CH]);
    f32x4 s3 = *reinterpret_cast<const f32x4*>(&P[i + 3 * CH]);
    const float r0 = drcp[c], r1 = drcp[ES + c], r2 = drcp[2 * ES + c], r3 = drcp[3 * ES + c];
    short4v o;
    #pragma unroll
    for (int j = 0; j < 4; ++j)
        o[j] = f2bf((s0[j] * r0 + s1[j] * r1) + (s2[j] * r2 + s3[j] * r3));
    *reinterpret_cast<short4v*>(&xt[i]) = o;
}

// ---------------- bf16 MFMA GEMM body ----------------
// BT path: gload_lds A+B dbuf, __syncthreads (round-8 proven).
// float-B path (FW = 4 or 2): VECTORIZED weight loads (f32x4 / f32x2 per lane) +
//   counted-vmcnt raw-barrier schedule. FW=4 requires ldb%4==0; FW=2 requires
//   ldb%2==0 and even Ndim (vector pairs never straddle the N bound).
// EPI: 0 none, 1 silu, 2 row-scale by aux[m].
// PADW: store n >= Ndim too (acc==0 there since B staged 0).
template<int BM, int BN, int EPI, bool NBND, bool KBND, bool BT, bool CT, bool PADW,
         int FW, typename TB, typename TC>
__device__ __forceinline__
void gemm_body(const short* __restrict__ A, const TB* __restrict__ B,
               TC* __restrict__ C, int Ndim, int Kdim,
               int lda, int ldb, int ldc,
               long sA, long sB, long sC, const float* __restrict__ aux)
{
    constexpr int BK = 32;
    A += (size_t)blockIdx.z * sA;
    B += (size_t)blockIdx.z * sB;
    C += (size_t)blockIdx.z * sC;
    const int m0 = blockIdx.x * BM;
    const int n0 = blockIdx.y * BN;
    const int tid  = threadIdx.x;
    const int lane = tid & 63;
    const int wid  = tid >> 6;
    const int wm = wid >> 1, wn = wid & 1;
    constexpr int WMT = BM / 2, WNT = BN / 2, MI = WMT / 16, NI = WNT / 16;
    constexpr int PA = BM / 64;
    constexpr int PB = BN / 64;

    __shared__ __align__(16) short As0[BM * 32], As1[BM * 32];
    __shared__ __align__(16) short Bs0[BN * 32], Bs1[BN * 32];

    f32x4 acc[MI][NI];
    #pragma unroll
    for (int mi = 0; mi < MI; ++mi)
        #pragma unroll
        for (int ni = 0; ni < NI; ++ni)
            acc[mi][ni] = (f32x4){0.f, 0.f, 0.f, 0.f};

    // float-B lane geometry
    const int fn = (FW == 4) ? (tid & 15) * 4 : (tid & 31) * 2;   // n offset
    const int fk = (FW == 4) ? (tid >> 4) * 2 : (tid >> 5) * 4;   // k offset

    // issue direct-to-LDS loads for A (and B when BT)
    auto ISSUEA = [&](short* ASP, short* BSP, int kk) {
        #pragma unroll
        for (int p = 0; p < PA; ++p) {
            const int slot = p * 256 + tid;
            const int row  = slot >> 2;
            const int seg  = (slot & 3) ^ ((row >> 1) & 3);
            GLD16(&A[(size_t)(m0 + row) * lda + kk + seg * 8],
                  &ASP[(p * 256 + wid * 64) * 8]);
        }
        if constexpr (BT) {
            #pragma unroll
            for (int p = 0; p < PB; ++p) {
                const int slot = p * 256 + tid;
                const int row  = slot >> 2;
                const int seg  = (slot & 3) ^ ((row >> 1) & 3);
                GLD16(&B[(size_t)(n0 + row) * ldb + kk + seg * 8],
                      &BSP[(p * 256 + wid * 64) * 8]);
            }
        }
    };

    // float-B: vectorized loads into named regs. FW=4: 2x f32x4 (rows k,k+1).
    // FW=2: 4x f32x2 (rows k..k+3), packed into the two f32x4 at compile-time slots.
    auto LOADB = [&](f32x4* bF, int kk) {
        const int n_ = n0 + fn;
        if constexpr (FW == 4) {
            #pragma unroll
            for (int r = 0; r < 2; ++r) {
                const int k_ = kk + fk + r;
                const bool ok = (!KBND) || (k_ < Kdim);
                bF[r] = ok ? *reinterpret_cast<const f32x4*>(&B[(size_t)k_ * ldb + n_])
                           : (f32x4){0.f, 0.f, 0.f, 0.f};
            }
        } else {
            const bool nok = (!NBND) || (n_ + 1 < Ndim);   // Ndim even: pair never straddles
            #pragma unroll
            for (int r = 0; r < 4; ++r) {
                const int k_ = kk + fk + r;
                const bool ok = nok && ((!KBND) || (k_ < Kdim));
                f32x2 v = ok ? *reinterpret_cast<const f32x2*>(&B[(size_t)k_ * ldb + n_])
                             : (f32x2){0.f, 0.f};
                bF[r >> 1][(r & 1) * 2]     = v[0];
                bF[r >> 1][(r & 1) * 2 + 1] = v[1];
            }
        }
    };

    auto PACKB = [&](short* BSP, const f32x4* bF) {
        if constexpr (FW == 4) {
            // 4 n-rows, 2 k's each -> u32 writes (within one 16B slot)
            #pragma unroll
            for (int i = 0; i < 4; ++i) {
                unsigned lo = (unsigned short)f2bf(bF[0][i]);
                unsigned hi = (unsigned short)f2bf(bF[1][i]);
                *reinterpret_cast<unsigned*>(&BSP[swz(fn + i, fk)]) = lo | (hi << 16);
            }
        } else {
            // 2 n-rows, 4 k's each -> short4 writes (8B, within one 16B slot)
            #pragma unroll
            for (int i = 0; i < 2; ++i) {
                short4v sv;
                #pragma unroll
                for (int r = 0; r < 4; ++r)
                    sv[r] = f2bf(bF[r >> 1][(r & 1) * 2 + i]);
                *reinterpret_cast<short4v*>(&BSP[swz(fn + i, fk)]) = sv;
            }
        }
    };

    auto COMPUTE = [&](const short* ASP, const short* BSP) {
        const int ar = lane & 15;
        const int ac = (lane >> 4) * 8;
        short8 af[MI], bf[NI];
        #pragma unroll
        for (int mi = 0; mi < MI; ++mi)
            af[mi] = *reinterpret_cast<const short8*>(&ASP[swz(wm * WMT + mi * 16 + ar, ac)]);
        #pragma unroll
        for (int ni = 0; ni < NI; ++ni)
            bf[ni] = *reinterpret_cast<const short8*>(&BSP[swz(wn * WNT + ni * 16 + ar, ac)]);
        #pragma unroll
        for (int mi = 0; mi < MI; ++mi)
            #pragma unroll
            for (int ni = 0; ni < NI; ++ni)
                acc[mi][ni] = __builtin_amdgcn_mfma_f32_16x16x32_bf16(
                    af[mi], bf[ni], acc[mi][ni], 0, 0, 0);
    };

    const int Kloop = KBND ? ((Kdim + 31) & ~31) : Kdim;
    const int nt = Kloop / BK;   // even, >= 2

    if constexpr (BT) {
        ISSUEA(As0, Bs0, 0);
        __syncthreads();
        for (int t = 0; t < nt; t += 2) {
            ISSUEA(As1, Bs1, (t + 1) * BK);
            COMPUTE(As0, Bs0);
            __syncthreads();
            const bool p2 = (t + 2 < nt);
            if (p2) ISSUEA(As0, Bs0, (t + 2) * BK);
            COMPUTE(As1, Bs1);
            __syncthreads();
        }
    } else {
        // counted-vmcnt raw-barrier schedule; only next-tile B loads (FW==4 ? 2 : 4)
        // stay in flight across each barrier.
        f32x4 bFa[2], bFb[2];
        LOADB(bFa, 0);
        __builtin_amdgcn_sched_barrier(0);
        ISSUEA(As0, Bs0, 0);
        __builtin_amdgcn_sched_barrier(0);
        LOADB(bFb, BK);
        PACKB(Bs0, bFa);
        if constexpr (FW == 4) asm volatile("s_waitcnt vmcnt(2) lgkmcnt(0)" ::: "memory");
        else                   asm volatile("s_waitcnt vmcnt(4) lgkmcnt(0)" ::: "memory");
        __builtin_amdgcn_s_barrier();

        for (int t = 0; t < nt; t += 2) {
            {
                ISSUEA(As1, Bs1, (t + 1) * BK);
                __builtin_amdgcn_sched_barrier(0);
                const bool pf = (t + 2 < nt);
                if (pf) LOADB(bFa, (t + 2) * BK);
                COMPUTE(As0, Bs0);
                PACKB(Bs1, bFb);
                if (pf) {
                    if constexpr (FW == 4) asm volatile("s_waitcnt vmcnt(2) lgkmcnt(0)" ::: "memory");
                    else                   asm volatile("s_waitcnt vmcnt(4) lgkmcnt(0)" ::: "memory");
                } else {
                    asm volatile("s_waitcnt vmcnt(0) lgkmcnt(0)" ::: "memory");
                }
                __builtin_amdgcn_s_barrier();
            }
            {
                const bool p2 = (t + 2 < nt);
                const bool p3 = (t + 3 < nt);
                if (p2) ISSUEA(As0, Bs0, (t + 2) * BK);
                __builtin_amdgcn_sched_barrier(0);
                if (p3) LOADB(bFb, (t + 3) * BK);
                COMPUTE(As1, Bs1);
                if (p2) PACKB(Bs0, bFa);
                if (p3) {
                    if constexpr (FW == 4) asm volatile("s_waitcnt vmcnt(2) lgkmcnt(0)" ::: "memory");
                    else                   asm volatile("s_waitcnt vmcnt(4) lgkmcnt(0)" ::: "memory");
                } else {
                    asm volatile("s_waitcnt vmcnt(0) lgkmcnt(0)" ::: "memory");
                }
                __builtin_amdgcn_s_barrier();
            }
        }
    }

    #pragma unroll
    for (int mi = 0; mi < MI; ++mi) {
        #pragma unroll
        for (int ni = 0; ni < NI; ++ni) {
            const int n = n0 + wn * WNT + ni * 16 + (lane & 15);
            if (NBND && !PADW && n >= Ndim) continue;
            const int mbase = m0 + wm * WMT + mi * 16 + (lane >> 4) * 4;
            if constexpr (CT) {
                short4v sv;
                #pragma unroll
                for (int r = 0; r < 4; ++r) sv[r] = f2bf(acc[mi][ni][r]);
                *reinterpret_cast<short4v*>(&C[(size_t)n * ldc + mbase]) = sv;
            } else {
                #pragma unroll
                for (int r = 0; r < 4; ++r) {
                    float v = acc[mi][ni][r];
                    if (EPI == 1)      v = v / (1.f + __expf(-v));   // silu
                    else if (EPI == 2) v = v * aux[mbase + r];       // crcp
                    if constexpr (sizeof(TC) == 2) C[(size_t)(mbase + r) * ldc + n] = f2bf(v);
                    else                           C[(size_t)(mbase + r) * ldc + n] = v;
                }
            }
        }
    }
}

// ---------------- named GEMM wrappers (round-8 tiles/grids) ----------------
__global__ __launch_bounds__(256) void g1_gemm(const short* A, const short* B, float* C) {
    gemm_body<128, 128, 0, false, false, true, false, false, 0, short, float>(
        A, B, C, HID, 2048, BS, BS, HID, 2048L, 2048L, (long)ES * HID, nullptr);
}
__global__ __launch_bounds__(256) void g1f_gemm(const short* A, const float* B, float* C) {
    gemm_body<128, 64, 0, false, false, false, false, false, 4, float, float>(
        A, B, C, HID, 2048, BS, HID, HID, 2048L, 2048L * HID, (long)ES * HID, nullptr);
}
__global__ __launch_bounds__(256) void g2_gemm(const short* A, const float* B, short* C) {
    gemm_body<128, 64, 1, true, false, false, false, true, 2, float, short>(
        A, B, C, FFN, HID, HID, FFN, FFNP,
        (long)SLOT * HID, (long)HID * FFN, (long)SLOT * FFNP, nullptr);
}
__global__ __launch_bounds__(256) void g3_gemm(const short* A, const float* B, short* C) {
    gemm_body<64, 64, 0, false, true, false, true, false, 4, float, short>(
        A, B, C, HID, FFN, FFNP, HID, ES,
        (long)SLOT * FFNP, (long)FFN * HID, (long)SLOT, nullptr);
}
__global__ __launch_bounds__(256) void g4_gemm(const short* A, const short* B, float* C,
                                               const float* crcp) {
    gemm_body<128, 128, 2, false, false, true, false, false, 0, short, float>(
        A, B, C, HID, ES, ES, ES, HID, 0, 0, 0, crcp);
}

// ---------------- launch ----------------

extern "C" void kernel_launch(void* const* d_in, const int* in_sizes, int n_in,
                              void* d_out, int out_size, void* d_ws, size_t ws_size,
                              hipStream_t stream)
{
    const float* x      = (const float*)d_in[0];
    const float* logits = (const float*)d_in[1];   // [BS][ES]
    const float* w_up   = (const float*)d_in[2];   // [16][1024][2730]
    const float* w_down = (const float*)d_in[3];   // [16][2730][1024]
    float* y = (float*)d_out;

    float* wsf     = (float*)d_ws;
    float* drcp    = wsf;                               // 4*2048
    float* crcp    = wsf + 8192;                        // 8192
    float* rowpart = wsf + 16384;                       // 8192*32
    float* colpart = rowpart + (size_t)8192 * 32;       // 32*2048
    short* DT      = (short*)(colpart + (size_t)32 * 2048);  // [2048][8192] bf16
    short* CB      = DT + (size_t)ES * BS;              // [8192][2048] bf16
    float* part    = (float*)(CB + (size_t)BS * ES);    // [4][2048][1024] fp32
    short* xt      = (short*)(part + (size_t)4 * ES * HID); // [2048][1024] bf16
    short* h       = xt + (size_t)ES * HID;             // [16][128][2752] bf16
    short* eoutT   = h + (size_t)NEXP * SLOT * FFNP;    // [1024][2048] bf16
    short* xT      = eoutT + (size_t)HID * ES;          // [1024][8192] bf16
    const size_t need_full = (size_t)((char*)(xT + (size_t)HID * BS) - (char*)d_ws);
    const bool use_bt = ws_size >= need_full;

    // NOTE: no memset. h pad columns (2730..2751) written as exact zeros by g2 (PADW).

    exp_stats_kernel<<<1024, 256, 0, stream>>>(logits, DT, CB, rowpart, colpart);
    rrow_kernel<<<32, 256, 0, stream>>>(rowpart, crcp);
    rcol_kernel<<<32, 256, 0, stream>>>(colpart, drcp);

    // G1: part[z] = expDT[:, batch z] @ x[batch z]   (K-split = batch x4, nt=64)
    if (use_bt) {
        transpose_x<<<dim3(128, 16, 1), 256, 0, stream>>>(x, xT);
        g1_gemm<<<dim3(16, 8, 4), 256, 0, stream>>>(DT, xT, part);
    } else {
        g1f_gemm<<<dim3(16, 16, 4), 256, 0, stream>>>(DT, x, part);
    }

    // xt = bf16(sum_z drcp[z] * part[z])
    reduce_xt<<<2048, 256, 0, stream>>>(part, drcp, xt);

    // G2: h[e] = silu(xt_e @ w_up_e), pad cols written as 0   (nt=32, f32x2 B loads)
    g2_gemm<<<dim3(1, 43, NEXP), 256, 0, stream>>>(xt, w_up, h);

    // G3: eoutT = (h_e @ w_down_e)^T   (nt=86, f32x4 B loads)
    g3_gemm<<<dim3(2, 16, NEXP), 256, 0, stream>>>(h, w_down, eoutT);

    // G4: y = expCB @ eout, row-scaled by crcp   (nt=64)
    g4_gemm<<<dim3(64, 8, 1), 256, 0, stream>>>(CB, eoutT, y, crcp);
}